// Round 4
// baseline (105.207 us; speedup 1.0000x reference)
//
#include <hip/hip_runtime.h>
#include <hip/hip_bf16.h>

typedef __bf16 bf16;
typedef __attribute__((ext_vector_type(8))) __bf16 bf16x8;
typedef __attribute__((ext_vector_type(4))) float floatx4;

#define PP 16
#define PPW 9
#define CFEAT 432      // C*P*PW = 3*16*9
#define EDIM 768
#define KDIM 768       // C*P*P = 3*256
#define NPAT 196
#define NBATCH 128
#define MROWS (NBATCH * NPAT)  // 25088

__device__ inline void gload16(const void* g, void* l) {
  __builtin_amdgcn_global_load_lds(
      (const __attribute__((address_space(1))) void*)g,
      (__attribute__((address_space(3))) void*)l, 16, 0, 0);
}

// ---------------------------------------------------------------------------
// Kernel 1: fold rfft2(ortho).real * fwh * fww into proj_w -> W_eff (bf16)
// W_eff[e][c*256 + h*16 + w] =
//   (1/16) * sum_{u,v} proj_w[e][c*144+u*9+v] * fwh[u]*fww[v]*cos(2pi(uh+vw)/16)
// ---------------------------------------------------------------------------
__global__ __launch_bounds__(256) void build_w_kernel(
    const float* __restrict__ pw, const float* __restrict__ fwh,
    const float* __restrict__ fww, bf16* __restrict__ Wb) {
  __shared__ float s_pw[144];
  __shared__ float s_fh[16];
  __shared__ float s_fw[9];
  __shared__ float s_cos[16];
  const int blk = blockIdx.x;
  const int e = blk / 3;
  const int c = blk % 3;
  const int t = threadIdx.x;
  if (t < 144) s_pw[t] = pw[e * CFEAT + c * 144 + t];
  if (t < 16) {
    s_fh[t] = fwh[t];
    s_cos[t] = cosf((float)t * 0.39269908169872414f);  // 2*pi/16
  }
  if (t < 9) s_fw[t] = fww[t];
  __syncthreads();
  const int h = t >> 4, w = t & 15;
  float acc = 0.f;
#pragma unroll
  for (int u = 0; u < 16; ++u) {
    const float fh = s_fh[u];
    const int uh = (u * h) & 15;
#pragma unroll
    for (int v = 0; v < 9; ++v) {
      acc += s_pw[u * 9 + v] * s_fw[v] * s_cos[(uh + v * w) & 15] * fh;
    }
  }
  Wb[e * KDIM + c * 256 + t] = (bf16)(acc * 0.0625f);
}

// ---------------------------------------------------------------------------
// Kernel 2: FUSED unfold + GEMM.  C[row][e] = sum_k A[row][k]*Wb[e][k] where
// A[row][c*256+hh*16+ww] = x[b][c][ph*16+hh][pw*16+ww] (row=b*196+ph*14+pw),
// A tile reg-staged from fp32 x with T14 async split (issue loads early,
// cvt+ds_write after compute); B tile staged via global_load_lds width-16.
// 128x128 tile, 4 waves of 64x64, BK=32, double-buffered LDS, 1 barrier/iter.
// Epilogue adds proj_b + pos_emb and scatters past the cls row.
// ---------------------------------------------------------------------------
__global__ __launch_bounds__(256) void gemm_fused_kernel(
    const float* __restrict__ x, const bf16* __restrict__ Wb,
    const float* __restrict__ pb, const float* __restrict__ pos,
    float* __restrict__ out) {
  __shared__ __align__(16) bf16 sA[2][128 * 32];
  __shared__ __align__(16) bf16 sB[2][128 * 32];

  const int nt = blockIdx.x;  // 0..5
  const int mt = blockIdx.y;  // 0..195
  const int t = threadIdx.x;
  const int l = t & 63;
  const int wv = t >> 6;
  const int wm = wv >> 1, wn = wv & 1;
  const int sub = t & 3;  // k-chunk: 8 elems at sub*8 within BK=32

  // --- A staging bases (loop-invariant per thread) ---
  // thread t stages rows r0 = mt*128 + (t>>2) and r1 = r0+64, k-chunk sub*8.
  // k = c*256 + hh*16 + ww ; per-kt: c = kt>>3 (uniform), hh = ((2kt)&15) +
  // (sub>>1), ww = (sub&1)*8.  Per-thread base holds (b, ph, pw, sub) parts.
  const int r0 = mt * 128 + (t >> 2);
  const int r1 = r0 + 64;
  const int b0 = r0 / 196, np0 = r0 - b0 * 196;
  const int b1 = r1 / 196, np1 = r1 - b1 * 196;
  const int ph0 = np0 / 14, pw0 = np0 - ph0 * 14;
  const int ph1 = np1 / 14, pw1 = np1 - ph1 * 14;
  const float* base0 = x + ((size_t)b0 * 3 * 224 + ph0 * 16 + (sub >> 1)) * 224 +
                       pw0 * 16 + (sub & 1) * 8;
  const float* base1 = x + ((size_t)b1 * 3 * 224 + ph1 * 16 + (sub >> 1)) * 224 +
                       pw1 * 16 + (sub & 1) * 8;

  // --- B staging (global_load_lds, wave-uniform LDS base) ---
  const bf16* gB = Wb + ((size_t)(nt * 128) + (t >> 2)) * KDIM + sub * 8;
  const size_t rstep = (size_t)64 * KDIM;
  const int lbase = wv * 512;  // elems; HW adds lane*16B

  floatx4 acc[4][4];
#pragma unroll
  for (int i = 0; i < 4; ++i)
#pragma unroll
    for (int j = 0; j < 4; ++j) acc[i][j] = (floatx4){0.f, 0.f, 0.f, 0.f};

  const int lr = l & 15;
  const int lk = (l >> 4) * 8;

  // x element offset for K-step kt (wave-uniform): c*224*224 + hh_base*224
#define KOFF(kt) (((kt) >> 3) * 50176 + (((kt)*2) & 15) * 224)

#define LOADA(kt, p00, p01, p10, p11)                                   \
  do {                                                                  \
    const int off = KOFF(kt);                                           \
    p00 = *reinterpret_cast<const float4*>(base0 + off);                \
    p01 = *reinterpret_cast<const float4*>(base0 + off + 4);            \
    p10 = *reinterpret_cast<const float4*>(base1 + off);                \
    p11 = *reinterpret_cast<const float4*>(base1 + off + 4);            \
  } while (0)

#define WRITEA(buf, p00, p01, p10, p11)                         \
  do {                                                          \
    bf16x8 a0, a1;                                              \
    a0[0] = (bf16)p00.x; a0[1] = (bf16)p00.y;                   \
    a0[2] = (bf16)p00.z; a0[3] = (bf16)p00.w;                   \
    a0[4] = (bf16)p01.x; a0[5] = (bf16)p01.y;                   \
    a0[6] = (bf16)p01.z; a0[7] = (bf16)p01.w;                   \
    a1[0] = (bf16)p10.x; a1[1] = (bf16)p10.y;                   \
    a1[2] = (bf16)p10.z; a1[3] = (bf16)p10.w;                   \
    a1[4] = (bf16)p11.x; a1[5] = (bf16)p11.y;                   \
    a1[6] = (bf16)p11.z; a1[7] = (bf16)p11.w;                   \
    *reinterpret_cast<bf16x8*>(&sA[buf][t * 8]) = a0;           \
    *reinterpret_cast<bf16x8*>(&sA[buf][2048 + t * 8]) = a1;    \
  } while (0)

#define STAGEB(buf, ko)                                  \
  do {                                                   \
    gload16(gB + (ko), &sB[buf][lbase]);                 \
    gload16(gB + rstep + (ko), &sB[buf][2048 + lbase]);  \
  } while (0)

#define COMPUTE(buf)                                              \
  do {                                                            \
    bf16x8 af[4], bfr[4];                                         \
    _Pragma("unroll") for (int mi = 0; mi < 4; ++mi) af[mi] =     \
        *reinterpret_cast<const bf16x8*>(                         \
            &sA[buf][(wm * 64 + mi * 16 + lr) * 32 + lk]);        \
    _Pragma("unroll") for (int ni = 0; ni < 4; ++ni) bfr[ni] =    \
        *reinterpret_cast<const bf16x8*>(                         \
            &sB[buf][(wn * 64 + ni * 16 + lr) * 32 + lk]);        \
    _Pragma("unroll") for (int mi = 0; mi < 4; ++mi)              \
        _Pragma("unroll") for (int ni = 0; ni < 4; ++ni) acc[mi]  \
            [ni] = __builtin_amdgcn_mfma_f32_16x16x32_bf16(       \
                af[mi], bfr[ni], acc[mi][ni], 0, 0, 0);           \
  } while (0)

  // prologue: stage tile 0 into buf 0
  {
    float4 p00, p01, p10, p11;
    LOADA(0, p00, p01, p10, p11);
    STAGEB(0, 0);
    WRITEA(0, p00, p01, p10, p11);
    __syncthreads();
  }

  int cur = 0;
  for (int kt = 0; kt < 23; ++kt) {
    float4 p00, p01, p10, p11;
    LOADA(kt + 1, p00, p01, p10, p11);   // issue early: latency hides under compute
    STAGEB(cur ^ 1, (kt + 1) * 32);
    COMPUTE(cur);
    WRITEA(cur ^ 1, p00, p01, p10, p11); // write late (T14 split)
    __syncthreads();                     // drains vmcnt (B) + lgkm (A writes)
    cur ^= 1;
  }
  COMPUTE(cur);

#undef KOFF
#undef LOADA
#undef WRITEA
#undef STAGEB
#undef COMPUTE

  // epilogue: out[b][1+n][e] = acc + proj_b[e] + pos_emb[1+n][e]
  float pbv[4];
#pragma unroll
  for (int ni = 0; ni < 4; ++ni)
    pbv[ni] = pb[nt * 128 + wn * 64 + ni * 16 + (l & 15)];

#pragma unroll
  for (int mi = 0; mi < 4; ++mi) {
#pragma unroll
    for (int j = 0; j < 4; ++j) {
      const unsigned m = wm * 64 + mi * 16 + ((l >> 4) << 2) + j;
      const unsigned Rr = mt * 128u + m;
      const unsigned b2 = Rr / 196u;
      const unsigned np2 = Rr - b2 * 196u;
      float* orow = out + ((size_t)b2 * 197 + 1 + np2) * 768;
      const float* prow = pos + (size_t)(1 + np2) * 768;
#pragma unroll
      for (int ni = 0; ni < 4; ++ni) {
        const int e = nt * 128 + wn * 64 + ni * 16 + (l & 15);
        orow[e] = acc[mi][ni][j] + pbv[ni] + prow[e];
      }
    }
  }
}

// ---------------------------------------------------------------------------
// Kernel 3: cls row  out[b][0][e] = cls[e] + pos_emb[0][e]
// ---------------------------------------------------------------------------
__global__ __launch_bounds__(256) void cls_kernel(
    const float* __restrict__ cls, const float* __restrict__ pos,
    float* __restrict__ out) {
  const int idx = blockIdx.x * 256 + threadIdx.x;
  const int b = idx / 768;
  const int e = idx - b * 768;
  out[(size_t)b * 197 * 768 + e] = cls[e] + pos[e];
}

extern "C" void kernel_launch(void* const* d_in, const int* in_sizes, int n_in,
                              void* d_out, int out_size, void* d_ws,
                              size_t ws_size, hipStream_t stream) {
  const float* x = (const float*)d_in[0];
  const float* fwh = (const float*)d_in[1];
  const float* fww = (const float*)d_in[2];
  const float* proj_w = (const float*)d_in[3];
  const float* proj_b = (const float*)d_in[4];
  const float* cls = (const float*)d_in[5];
  const float* pos = (const float*)d_in[6];
  float* out = (float*)d_out;

  bf16* Wb = (bf16*)d_ws;  // 768*768*2 = 1.18 MB

  build_w_kernel<<<EDIM * 3, 256, 0, stream>>>(proj_w, fwh, fww, Wb);
  cls_kernel<<<(NBATCH * EDIM) / 256, 256, 0, stream>>>(cls, pos, out);
  gemm_fused_kernel<<<dim3(6, 196), 256, 0, stream>>>(x, Wb, proj_b, pos, out);
}

// Round 5
// 77.798 us; speedup vs baseline: 1.3523x; 1.3523x over previous
//
#include <hip/hip_runtime.h>
#include <hip/hip_bf16.h>

typedef __bf16 bf16;
typedef __attribute__((ext_vector_type(8))) __bf16 bf16x8;
typedef __attribute__((ext_vector_type(4))) float floatx4;

#define PP 16
#define PPW 9
#define CFEAT 432      // C*P*PW = 3*16*9
#define EDIM 768
#define KDIM 768       // C*P*P = 3*256
#define NPAT 196
#define NBATCH 128
#define MROWS (NBATCH * NPAT)  // 25088

// prep_kernel block ranges
#define NB_W 2304                 // build_w: 768*3
#define NB_CLS 384                // cls: 128*768/256
#define NB_UNF 9408               // unfold: 25088*768/8/256
#define NB_PREP (NB_W + NB_CLS + NB_UNF)

__device__ inline void gload16(const void* g, void* l) {
  __builtin_amdgcn_global_load_lds(
      (const __attribute__((address_space(1))) void*)g,
      (__attribute__((address_space(3))) void*)l, 16, 0, 0);
}

// ---------------------------------------------------------------------------
// Kernel 1 (merged prep):
//   blocks [0, NB_W)           : W_eff[e][c*256+h*16+w] = folded DFT*freq*proj
//   blocks [NB_W, +NB_CLS)     : out[b][0][e] = cls[e] + pos[0][e]
//   blocks [NB_W+NB_CLS, end)  : A[b*196+n][c*256+h2*16+w2] = bf16(x[b][c][h][w])
// All three are independent; merged to cut launch gaps.
// ---------------------------------------------------------------------------
__global__ __launch_bounds__(256) void prep_kernel(
    const float* __restrict__ x, const float* __restrict__ pw,
    const float* __restrict__ fwh, const float* __restrict__ fww,
    const float* __restrict__ cls, const float* __restrict__ pos,
    bf16* __restrict__ Wb, bf16* __restrict__ A, float* __restrict__ out) {
  const int blk = blockIdx.x;
  const int t = threadIdx.x;

  if (blk >= NB_W + NB_CLS) {  // ---- unfold (bulk path) ----
    const int i = (blk - NB_W - NB_CLS) * 256 + t;  // < 2408448
    const int w8 = i % 28;
    const int tmp = i / 28;
    const int h = tmp % 224;
    const int tmp2 = tmp / 224;
    const int c = tmp2 % 3;
    const int b = tmp2 / 3;
    const float4 f0 = *reinterpret_cast<const float4*>(x + (size_t)i * 8);
    const float4 f1 = *reinterpret_cast<const float4*>(x + (size_t)i * 8 + 4);
    bf16x8 v;
    v[0] = (bf16)f0.x; v[1] = (bf16)f0.y; v[2] = (bf16)f0.z; v[3] = (bf16)f0.w;
    v[4] = (bf16)f1.x; v[5] = (bf16)f1.y; v[6] = (bf16)f1.z; v[7] = (bf16)f1.w;
    const int row = b * NPAT + (h >> 4) * 14 + (w8 >> 1);
    const int k = c * 256 + (h & 15) * 16 + (w8 & 1) * 8;
    *reinterpret_cast<bf16x8*>(A + (size_t)row * KDIM + k) = v;
  } else if (blk < NB_W) {  // ---- build W_eff ----
    __shared__ float s_pw[144];
    __shared__ float s_fh[16];
    __shared__ float s_fw[9];
    __shared__ float s_cos[16];
    const int e = blk / 3;
    const int c = blk % 3;
    if (t < 144) s_pw[t] = pw[e * CFEAT + c * 144 + t];
    if (t < 16) {
      s_fh[t] = fwh[t];
      s_cos[t] = cosf((float)t * 0.39269908169872414f);  // 2*pi/16
    }
    if (t < 9) s_fw[t] = fww[t];
    __syncthreads();
    const int h = t >> 4, w = t & 15;
    float acc = 0.f;
#pragma unroll
    for (int u = 0; u < 16; ++u) {
      const float fh = s_fh[u];
      const int uh = (u * h) & 15;
#pragma unroll
      for (int v = 0; v < 9; ++v) {
        acc += s_pw[u * 9 + v] * s_fw[v] * s_cos[(uh + v * w) & 15] * fh;
      }
    }
    Wb[e * KDIM + c * 256 + t] = (bf16)(acc * 0.0625f);
  } else {  // ---- cls row ----
    const int idx = (blk - NB_W) * 256 + t;  // < 128*768
    const int b = idx / 768;
    const int e = idx - b * 768;
    out[(size_t)b * 197 * 768 + e] = cls[e] + pos[e];
  }
}

// ---------------------------------------------------------------------------
// Kernel 2: main GEMM, double-buffered prefetch (1 barrier/iter) + T1 XCD
// swizzle: grid is 1D 1176 = 8 XCDs x 147; swz=(bid&7)*147+(bid>>3) gives each
// XCD a contiguous swz chunk; swz = mt*6+nt keeps all 6 nt-blocks of an
// A-panel on ONE XCD -> panel fetched once into that L2, 5 hits.
// 128x128 tile, 4 waves of 64x64, BK=32, global_load_lds width-16 staging.
// ---------------------------------------------------------------------------
__global__ __launch_bounds__(256) void gemm_db_kernel(
    const bf16* __restrict__ A, const bf16* __restrict__ Wb,
    const float* __restrict__ pb, const float* __restrict__ pos,
    float* __restrict__ out) {
  __shared__ __align__(16) bf16 sA[2][128 * 32];
  __shared__ __align__(16) bf16 sB[2][128 * 32];

  const int bid = blockIdx.x;                    // 0..1175
  const int swz = (bid & 7) * 147 + (bid >> 3);  // XCD-chunked, bijective
  const int mt = swz / 6;                        // 0..195
  const int nt = swz - mt * 6;                   // 0..5
  const int t = threadIdx.x;
  const int l = t & 63;
  const int wv = t >> 6;
  const int wm = wv >> 1, wn = wv & 1;

  // staging: thread t covers bytes [t*16, t*16+16) of each 4KB half-tile
  const bf16* gA = A + ((size_t)(mt * 128) + (t >> 2)) * KDIM + (t & 3) * 8;
  const bf16* gB = Wb + ((size_t)(nt * 128) + (t >> 2)) * KDIM + (t & 3) * 8;
  const size_t rstep = (size_t)64 * KDIM;
  const int lbase = wv * 512;  // wave-uniform LDS base (elems); HW adds lane*16B

#define STAGE(buf, ko)                                  \
  do {                                                  \
    gload16(gA + (ko), &sA[buf][lbase]);                \
    gload16(gA + rstep + (ko), &sA[buf][2048 + lbase]); \
    gload16(gB + (ko), &sB[buf][lbase]);                \
    gload16(gB + rstep + (ko), &sB[buf][2048 + lbase]); \
  } while (0)

  floatx4 acc[4][4];
#pragma unroll
  for (int i = 0; i < 4; ++i)
#pragma unroll
    for (int j = 0; j < 4; ++j) acc[i][j] = (floatx4){0.f, 0.f, 0.f, 0.f};

  const int lr = l & 15;
  const int lk = (l >> 4) * 8;  // k-element offset of this lane's frag

#define COMPUTE(buf)                                              \
  do {                                                            \
    bf16x8 af[4], bfr[4];                                         \
    _Pragma("unroll") for (int mi = 0; mi < 4; ++mi) af[mi] =     \
        *reinterpret_cast<const bf16x8*>(                         \
            &sA[buf][(wm * 64 + mi * 16 + lr) * 32 + lk]);        \
    _Pragma("unroll") for (int ni = 0; ni < 4; ++ni) bfr[ni] =    \
        *reinterpret_cast<const bf16x8*>(                         \
            &sB[buf][(wn * 64 + ni * 16 + lr) * 32 + lk]);        \
    _Pragma("unroll") for (int mi = 0; mi < 4; ++mi)              \
        _Pragma("unroll") for (int ni = 0; ni < 4; ++ni) acc[mi]  \
            [ni] = __builtin_amdgcn_mfma_f32_16x16x32_bf16(       \
                af[mi], bfr[ni], acc[mi][ni], 0, 0, 0);           \
  } while (0)

  STAGE(0, 0);
  __syncthreads();
  int cur = 0;
  for (int kt = 0; kt < 23; ++kt) {
    STAGE(cur ^ 1, (kt + 1) * 32);  // prefetch next tile (in flight thru compute)
    COMPUTE(cur);
    __syncthreads();  // vmcnt(0)+lgkmcnt(0) drain AFTER compute
    cur ^= 1;
  }
  COMPUTE(cur);
#undef STAGE
#undef COMPUTE

  // epilogue: out[b][1+n][e] = acc + proj_b[e] + pos_emb[1+n][e]
  float pbv[4];
#pragma unroll
  for (int ni = 0; ni < 4; ++ni)
    pbv[ni] = pb[nt * 128 + wn * 64 + ni * 16 + (l & 15)];

#pragma unroll
  for (int mi = 0; mi < 4; ++mi) {
#pragma unroll
    for (int j = 0; j < 4; ++j) {
      const unsigned m = wm * 64 + mi * 16 + ((l >> 4) << 2) + j;
      const unsigned Rr = mt * 128u + m;
      const unsigned b2 = Rr / 196u;
      const unsigned np2 = Rr - b2 * 196u;
      float* orow = out + ((size_t)b2 * 197 + 1 + np2) * 768;
      const float* prow = pos + (size_t)(1 + np2) * 768;
#pragma unroll
      for (int ni = 0; ni < 4; ++ni) {
        const int e = nt * 128 + wn * 64 + ni * 16 + (l & 15);
        orow[e] = acc[mi][ni][j] + pbv[ni] + prow[e];
      }
    }
  }
}

extern "C" void kernel_launch(void* const* d_in, const int* in_sizes, int n_in,
                              void* d_out, int out_size, void* d_ws,
                              size_t ws_size, hipStream_t stream) {
  const float* x = (const float*)d_in[0];
  const float* fwh = (const float*)d_in[1];
  const float* fww = (const float*)d_in[2];
  const float* proj_w = (const float*)d_in[3];
  const float* proj_b = (const float*)d_in[4];
  const float* cls = (const float*)d_in[5];
  const float* pos = (const float*)d_in[6];
  float* out = (float*)d_out;

  const size_t needW = (size_t)EDIM * KDIM * sizeof(bf16);   // 1.18 MB
  bf16* Wb = (bf16*)d_ws;
  bf16* A = (bf16*)((char*)d_ws + needW);                    // 38.5 MB

  prep_kernel<<<NB_PREP, 256, 0, stream>>>(x, proj_w, fwh, fww, cls, pos, Wb,
                                           A, out);
  gemm_db_kernel<<<1176, 256, 0, stream>>>(A, Wb, proj_b, pos, out);
}